// Round 1
// baseline (375.561 us; speedup 1.0000x reference)
//
#include <hip/hip_runtime.h>

#define DIM 160
#define PLANE 25600          // 160*160
#define NVOX 4096000         // 160^3
constexpr float INV_WS = 1.0f / 729.0f;

// ---------------------------------------------------------------------------
// Pass 1: per-voxel products (I, J, I^2, J^2, IJ) + 9-tap box sum along W.
// Block stages 8 contiguous W-lines of I and J in LDS.
// grid = 160*160/8 = 3200 blocks, 256 threads.
// ---------------------------------------------------------------------------
__global__ void pass1_kernel(const float* __restrict__ I, const float* __restrict__ J,
                             float* __restrict__ ws) {
    __shared__ float sI[8 * DIM];
    __shared__ float sJ[8 * DIM];
    const int tid = threadIdx.x;
    const int base = blockIdx.x * (8 * DIM);   // flat start of 8 lines

    #pragma unroll
    for (int j = 0; j < 5; ++j) {
        int o = tid + j * 256;
        sI[o] = I[base + o];
        sJ[o] = J[base + o];
    }
    __syncthreads();

    #pragma unroll
    for (int j = 0; j < 5; ++j) {
        int o = tid + j * 256;
        int r = o / DIM;
        int w = o - r * DIM;
        float s1 = 0.f, s2 = 0.f, s3 = 0.f, s4 = 0.f, s5 = 0.f;
        #pragma unroll
        for (int k = -4; k <= 4; ++k) {
            int ww = w + k;
            if (ww >= 0 && ww < DIM) {
                float a = sI[r * DIM + ww];
                float b = sJ[r * DIM + ww];
                s1 += a; s2 += b; s3 += a * a; s4 += b * b; s5 += a * b;
            }
        }
        int gi = base + o;
        ws[gi]            = s1;
        ws[NVOX + gi]     = s2;
        ws[2 * NVOX + gi] = s3;
        ws[3 * NVOX + gi] = s4;
        ws[4 * NVOX + gi] = s5;
    }
}

// ---------------------------------------------------------------------------
// Pass 2: 9-tap box sum along H, in-place on each of the 5 fields.
// Each block owns (d, w0..w0+31, all h); stages the full [160][32] tile in
// LDS before overwriting, so in-place is safe.
// grid = (160, 5), 256 threads = 32w x 8h.
// ---------------------------------------------------------------------------
__global__ void pass2_kernel(float* __restrict__ ws) {
    __shared__ float tile[DIM * 32];
    const int d  = blockIdx.x;
    const int w0 = blockIdx.y * 32;
    const int wi = threadIdx.x & 31;
    const int hg = threadIdx.x >> 5;   // 0..7

    for (int f = 0; f < 5; ++f) {
        float* fld = ws + f * NVOX;
        __syncthreads();   // protect LDS reuse from previous field's reads
        for (int hh = hg; hh < DIM; hh += 8) {
            tile[hh * 32 + wi] = fld[(d * DIM + hh) * DIM + w0 + wi];
        }
        __syncthreads();
        for (int h = hg; h < DIM; h += 8) {
            float s = 0.f;
            #pragma unroll
            for (int k = -4; k <= 4; ++k) {
                int hh = h + k;
                if (hh >= 0 && hh < DIM) s += tile[hh * 32 + wi];
            }
            fld[(d * DIM + h) * DIM + w0 + wi] = s;
        }
    }
}

// ---------------------------------------------------------------------------
// Pass 3: sliding 9-tap box sum along D + cc epilogue + reduction.
// Thread per (h,w) column, D chunked by blockIdx.y (8 chunks of 20).
// grid = (100, 8), 256 threads.
// ---------------------------------------------------------------------------
__global__ void pass3_kernel(const float* __restrict__ ws, double* __restrict__ acc) {
    const int hw = blockIdx.x * 256 + threadIdx.x;    // 0..25599
    const int d0 = blockIdx.y * 20;

    float S0 = 0.f, S1 = 0.f, S2 = 0.f, S3 = 0.f, S4 = 0.f;
    for (int dd = d0 - 4; dd <= d0 + 4; ++dd) {
        if (dd >= 0 && dd < DIM) {
            int gi = dd * PLANE + hw;
            S0 += ws[gi];
            S1 += ws[NVOX + gi];
            S2 += ws[2 * NVOX + gi];
            S3 += ws[3 * NVOX + gi];
            S4 += ws[4 * NVOX + gi];
        }
    }

    float local = 0.f;
    for (int d = d0; d < d0 + 20; ++d) {
        float cross = S4 - S0 * S1 * INV_WS;
        float Ivar  = S2 - S0 * S0 * INV_WS;
        float Jvar  = S3 - S1 * S1 * INV_WS;
        float cc = cross * cross / (Ivar * Jvar + 1e-5f);
        local += cc;
        int da = d + 5, dr = d - 4;
        if (da < DIM) {
            int gi = da * PLANE + hw;
            S0 += ws[gi];
            S1 += ws[NVOX + gi];
            S2 += ws[2 * NVOX + gi];
            S3 += ws[3 * NVOX + gi];
            S4 += ws[4 * NVOX + gi];
        }
        if (dr >= 0) {
            int gi = dr * PLANE + hw;
            S0 -= ws[gi];
            S1 -= ws[NVOX + gi];
            S2 -= ws[2 * NVOX + gi];
            S3 -= ws[3 * NVOX + gi];
            S4 -= ws[4 * NVOX + gi];
        }
    }

    for (int off = 32; off; off >>= 1) local += __shfl_down(local, off);
    if ((threadIdx.x & 63) == 0) atomicAdd(acc, (double)local);
}

// ---------------------------------------------------------------------------
// Gradient loss: sum of squared forward diffs along D/H/W of flow [3,160^3].
// All three means share denominator 3*159*160*160, so one fused sum works.
// ---------------------------------------------------------------------------
__global__ void grad_kernel(const float* __restrict__ s, double* __restrict__ acc) {
    const int total = 3 * NVOX;
    float local = 0.f;
    for (int i = blockIdx.x * blockDim.x + threadIdx.x; i < total;
         i += gridDim.x * blockDim.x) {
        int rem = i % NVOX;
        int d  = rem / PLANE;
        int r2 = rem - d * PLANE;
        int h  = r2 / DIM;
        int w  = r2 - h * DIM;
        float v = s[i];
        if (d < DIM - 1) { float t = s[i + PLANE] - v; local += t * t; }
        if (h < DIM - 1) { float t = s[i + DIM]   - v; local += t * t; }
        if (w < DIM - 1) { float t = s[i + 1]     - v; local += t * t; }
    }
    for (int off = 32; off; off >>= 1) local += __shfl_down(local, off);
    if ((threadIdx.x & 63) == 0) atomicAdd(acc + 1, (double)local);
}

// ---------------------------------------------------------------------------
// Final combine: loss = 10*ncc + 15*grad; out = [loss, ncc, grad].
// ---------------------------------------------------------------------------
__global__ void final_kernel(const double* __restrict__ acc, float* __restrict__ out) {
    double ncc  = -(acc[0] / 4096000.0);
    double grad = acc[1] / 36633600.0;     // sum / (3*159*160*160) / 3
    double loss = 10.0 * ncc + 15.0 * grad;
    out[0] = (float)loss;
    out[1] = (float)ncc;
    out[2] = (float)grad;
}

extern "C" void kernel_launch(void* const* d_in, const int* in_sizes, int n_in,
                              void* d_out, int out_size, void* d_ws, size_t ws_size,
                              hipStream_t stream) {
    const float* y    = (const float*)d_in[0];
    const float* tgt  = (const float*)d_in[1];
    // d_in[2] = src, unused by the reference
    const float* flow = (const float*)d_in[3];
    float* out = (float*)d_out;
    float* ws  = (float*)d_ws;
    double* acc = (double*)((char*)d_ws + (size_t)5 * NVOX * 4);  // 8-byte aligned

    hipMemsetAsync(acc, 0, 2 * sizeof(double), stream);

    // nas_ncc(I = tgt, J = y)
    pass1_kernel<<<NVOX / (8 * DIM), 256, 0, stream>>>(tgt, y, ws);
    dim3 g2(DIM, 5);
    pass2_kernel<<<g2, 256, 0, stream>>>(ws);
    dim3 g3(PLANE / 256, 8);
    pass3_kernel<<<g3, 256, 0, stream>>>(ws, acc);

    grad_kernel<<<2048, 256, 0, stream>>>(flow, acc);
    final_kernel<<<1, 1, 0, stream>>>(acc, out);
}

// Round 2
// 257.893 us; speedup vs baseline: 1.4563x; 1.4563x over previous
//
#include <hip/hip_runtime.h>

#define DIM 160
#define PLANE 25600          // 160*160
#define NVOX 4096000         // 160^3
constexpr float INV_WS = 1.0f / 729.0f;

#define NCC_WAVES 3200       // pass3: 800 blocks * 4 waves
#define GRAD_WAVES 8192      // grad: 2048 blocks * 4 waves

// ---------------------------------------------------------------------------
// Pass 1: per-voxel products (I, J, I^2, J^2, IJ) + 9-tap box sum along W.
// Block stages 8 contiguous W-lines of I and J in LDS.
// grid = 160*160/8 = 3200 blocks, 256 threads.
// ---------------------------------------------------------------------------
__global__ void pass1_kernel(const float* __restrict__ I, const float* __restrict__ J,
                             float* __restrict__ ws) {
    __shared__ float sI[8 * DIM];
    __shared__ float sJ[8 * DIM];
    const int tid = threadIdx.x;
    const int base = blockIdx.x * (8 * DIM);   // flat start of 8 lines

    #pragma unroll
    for (int j = 0; j < 5; ++j) {
        int o = tid + j * 256;
        sI[o] = I[base + o];
        sJ[o] = J[base + o];
    }
    __syncthreads();

    #pragma unroll
    for (int j = 0; j < 5; ++j) {
        int o = tid + j * 256;
        int r = o / DIM;
        int w = o - r * DIM;
        float s1 = 0.f, s2 = 0.f, s3 = 0.f, s4 = 0.f, s5 = 0.f;
        #pragma unroll
        for (int k = -4; k <= 4; ++k) {
            int ww = w + k;
            if (ww >= 0 && ww < DIM) {
                float a = sI[r * DIM + ww];
                float b = sJ[r * DIM + ww];
                s1 += a; s2 += b; s3 += a * a; s4 += b * b; s5 += a * b;
            }
        }
        int gi = base + o;
        ws[gi]            = s1;
        ws[NVOX + gi]     = s2;
        ws[2 * NVOX + gi] = s3;
        ws[3 * NVOX + gi] = s4;
        ws[4 * NVOX + gi] = s5;
    }
}

// ---------------------------------------------------------------------------
// Pass 2: 9-tap box sum along H, in-place on each of the 5 fields.
// Each block owns (d, w0..w0+31, all h); stages the full [160][32] tile in
// LDS before overwriting, so in-place is safe.
// grid = (160, 5), 256 threads = 32w x 8h.
// ---------------------------------------------------------------------------
__global__ void pass2_kernel(float* __restrict__ ws) {
    __shared__ float tile[DIM * 32];
    const int d  = blockIdx.x;
    const int w0 = blockIdx.y * 32;
    const int wi = threadIdx.x & 31;
    const int hg = threadIdx.x >> 5;   // 0..7

    for (int f = 0; f < 5; ++f) {
        float* fld = ws + f * NVOX;
        __syncthreads();   // protect LDS reuse from previous field's reads
        for (int hh = hg; hh < DIM; hh += 8) {
            tile[hh * 32 + wi] = fld[(d * DIM + hh) * DIM + w0 + wi];
        }
        __syncthreads();
        for (int h = hg; h < DIM; h += 8) {
            float s = 0.f;
            #pragma unroll
            for (int k = -4; k <= 4; ++k) {
                int hh = h + k;
                if (hh >= 0 && hh < DIM) s += tile[hh * 32 + wi];
            }
            fld[(d * DIM + h) * DIM + w0 + wi] = s;
        }
    }
}

// ---------------------------------------------------------------------------
// Pass 3: sliding 9-tap box sum along D + cc epilogue + per-wave partial.
// Thread per (h,w) column, D chunked by blockIdx.y (8 chunks of 20).
// grid = (100, 8), 256 threads. No atomics: wave partial -> unique slot.
// ---------------------------------------------------------------------------
__global__ void pass3_kernel(const float* __restrict__ ws, double* __restrict__ part) {
    const int hw = blockIdx.x * 256 + threadIdx.x;    // 0..25599
    const int d0 = blockIdx.y * 20;

    float S0 = 0.f, S1 = 0.f, S2 = 0.f, S3 = 0.f, S4 = 0.f;
    for (int dd = d0 - 4; dd <= d0 + 4; ++dd) {
        if (dd >= 0 && dd < DIM) {
            int gi = dd * PLANE + hw;
            S0 += ws[gi];
            S1 += ws[NVOX + gi];
            S2 += ws[2 * NVOX + gi];
            S3 += ws[3 * NVOX + gi];
            S4 += ws[4 * NVOX + gi];
        }
    }

    float local = 0.f;
    for (int d = d0; d < d0 + 20; ++d) {
        float cross = S4 - S0 * S1 * INV_WS;
        float Ivar  = S2 - S0 * S0 * INV_WS;
        float Jvar  = S3 - S1 * S1 * INV_WS;
        float cc = cross * cross / (Ivar * Jvar + 1e-5f);
        local += cc;
        int da = d + 5, dr = d - 4;
        if (da < DIM) {
            int gi = da * PLANE + hw;
            S0 += ws[gi];
            S1 += ws[NVOX + gi];
            S2 += ws[2 * NVOX + gi];
            S3 += ws[3 * NVOX + gi];
            S4 += ws[4 * NVOX + gi];
        }
        if (dr >= 0) {
            int gi = dr * PLANE + hw;
            S0 -= ws[gi];
            S1 -= ws[NVOX + gi];
            S2 -= ws[2 * NVOX + gi];
            S3 -= ws[3 * NVOX + gi];
            S4 -= ws[4 * NVOX + gi];
        }
    }

    for (int off = 32; off; off >>= 1) local += __shfl_down(local, off);
    if ((threadIdx.x & 63) == 0) {
        int wave = (blockIdx.y * gridDim.x + blockIdx.x) * 4 + (threadIdx.x >> 6);
        part[wave] = (double)local;
    }
}

// ---------------------------------------------------------------------------
// Gradient loss: sum of squared forward diffs along D/H/W of flow [3,160^3].
// Per-wave partials, no atomics.
// ---------------------------------------------------------------------------
__global__ void grad_kernel(const float* __restrict__ s, double* __restrict__ part) {
    const int total = 3 * NVOX;
    float local = 0.f;
    for (int i = blockIdx.x * blockDim.x + threadIdx.x; i < total;
         i += gridDim.x * blockDim.x) {
        int rem = i % NVOX;
        int d  = rem / PLANE;
        int r2 = rem - d * PLANE;
        int h  = r2 / DIM;
        int w  = r2 - h * DIM;
        float v = s[i];
        if (d < DIM - 1) { float t = s[i + PLANE] - v; local += t * t; }
        if (h < DIM - 1) { float t = s[i + DIM]   - v; local += t * t; }
        if (w < DIM - 1) { float t = s[i + 1]     - v; local += t * t; }
    }
    for (int off = 32; off; off >>= 1) local += __shfl_down(local, off);
    if ((threadIdx.x & 63) == 0) {
        int wave = blockIdx.x * 4 + (threadIdx.x >> 6);
        part[NCC_WAVES + wave] = (double)local;
    }
}

// ---------------------------------------------------------------------------
// Final combine: sum partials; loss = 10*ncc + 15*grad; out = [loss, ncc, grad].
// One 256-thread block.
// ---------------------------------------------------------------------------
__global__ void final_kernel(const double* __restrict__ part, float* __restrict__ out) {
    __shared__ double s_n[4], s_g[4];
    double n = 0.0, g = 0.0;
    for (int i = threadIdx.x; i < NCC_WAVES; i += 256) n += part[i];
    for (int i = threadIdx.x; i < GRAD_WAVES; i += 256) g += part[NCC_WAVES + i];
    for (int off = 32; off; off >>= 1) {
        n += __shfl_down(n, off);
        g += __shfl_down(g, off);
    }
    if ((threadIdx.x & 63) == 0) {
        s_n[threadIdx.x >> 6] = n;
        s_g[threadIdx.x >> 6] = g;
    }
    __syncthreads();
    if (threadIdx.x == 0) {
        double ncc_sum  = s_n[0] + s_n[1] + s_n[2] + s_n[3];
        double grad_sum = s_g[0] + s_g[1] + s_g[2] + s_g[3];
        double ncc  = -(ncc_sum / 4096000.0);
        double grad = grad_sum / 36633600.0;   // sum / (3*159*160*160) / 3
        double loss = 10.0 * ncc + 15.0 * grad;
        out[0] = (float)loss;
        out[1] = (float)ncc;
        out[2] = (float)grad;
    }
}

extern "C" void kernel_launch(void* const* d_in, const int* in_sizes, int n_in,
                              void* d_out, int out_size, void* d_ws, size_t ws_size,
                              hipStream_t stream) {
    const float* y    = (const float*)d_in[0];
    const float* tgt  = (const float*)d_in[1];
    // d_in[2] = src, unused by the reference
    const float* flow = (const float*)d_in[3];
    float* out = (float*)d_out;
    float* ws  = (float*)d_ws;
    // partials live after the 5 fields; 5*NVOX*4 = 81,920,000 (8-byte aligned)
    double* part = (double*)((char*)d_ws + (size_t)5 * NVOX * 4);

    // nas_ncc(I = tgt, J = y)
    pass1_kernel<<<NVOX / (8 * DIM), 256, 0, stream>>>(tgt, y, ws);
    dim3 g2(DIM, 5);
    pass2_kernel<<<g2, 256, 0, stream>>>(ws);
    dim3 g3(PLANE / 256, 8);
    pass3_kernel<<<g3, 256, 0, stream>>>(ws, part);

    grad_kernel<<<2048, 256, 0, stream>>>(flow, part);
    final_kernel<<<1, 256, 0, stream>>>(part, out);
}

// Round 4
// 180.304 us; speedup vs baseline: 2.0829x; 1.4303x over previous
//
#include <hip/hip_runtime.h>

#define DIM 160
#define PLANE 25600          // 160*160
#define NVOX 4096000         // 160^3
constexpr float INV_WS = 1.0f / 729.0f;

#define TW 32                // output tile width  (W)
#define TH 16                // output tile height (H)
#define DC 16                // output depth chunk (D)
#define HW 40                // TW+8 halo width
#define HH 24                // TH+8 halo height
#define PSTR 41              // prod row stride (pad: kills 16-way conflicts)
#define WSTR 33              // wsum row stride (pad: kills 16-way conflicts)

#define NCC_WAVES 4000       // 5*10*10 blocks * 8 waves
#define GRAD_WAVES 4096      // 1024 blocks * 4 waves

// ---------------------------------------------------------------------------
// Fused NCC: per block, one 16x32x16 output tile. Per D-slice:
//   global(I,J halo) -> 5 products (LDS) -> sliding W-boxsum (LDS) ->
//   H-boxsum (regs) -> 9-deep D-ring (regs, static slots) -> cc -> partial.
// 512 threads (8 waves). grid = (5, 10, 10).
// ---------------------------------------------------------------------------
__global__ __launch_bounds__(512)
void ncc_fused_kernel(const float* __restrict__ I, const float* __restrict__ J,
                      double* __restrict__ part) {
    __shared__ float prod[5][HH * PSTR];   // 19.7 KB
    __shared__ float wsum[5][HH * WSTR];   // 15.8 KB

    const int tid = threadIdx.x;
    const int w0 = blockIdx.x * TW;
    const int h0 = blockIdx.y * TH;
    const int d0 = blockIdx.z * DC;
    const int wi = tid & 31;       // output col within tile
    const int hi = tid >> 5;       // output row within tile (0..15)

    // --- load-position decode (960 halo positions, 2 per thread) ---
    const int p0 = tid;
    const int r0 = p0 / HW, c0 = p0 - r0 * HW;
    const int p1 = tid + 512;
    const int r1 = p1 / HW, c1 = p1 - r1 * HW;
    const int gr0 = h0 - 4 + r0, gc0 = w0 - 4 + c0;
    const int gr1 = h0 - 4 + r1, gc1 = w0 - 4 + c1;
    const bool v0 = (gr0 >= 0 && gr0 < DIM && gc0 >= 0 && gc0 < DIM);
    const bool v1 = (p1 < HH * HW) && (gr1 >= 0 && gr1 < DIM && gc1 >= 0 && gc1 < DIM);
    const int off0 = gr0 * DIM + gc0;      // within-slice offset
    const int off1 = gr1 * DIM + gc1;

    // --- W-sum task decode: 480 tasks = field(5) x halo-row(24) x segment(4) ---
    const int tf   = tid / 96;                  // field
    const int trm  = tid - tf * 96;
    const int tr   = trm >> 2;                  // halo row 0..23
    const int tseg = (trm & 3) * 8;             // output col segment start

    float S[5][9];                              // D-ring (static slots only)
    #pragma unroll
    for (int f = 0; f < 5; ++f)
        #pragma unroll
        for (int s = 0; s < 9; ++s) S[f][s] = 0.f;
    float R[5] = {0.f, 0.f, 0.f, 0.f, 0.f};    // running window sums
    float local = 0.f;

    for (int k0 = 0; k0 < DC + 8; k0 += 9) {   // 3 outer iters; slot = j static
        #pragma unroll
        for (int j = 0; j < 9; ++j) {
            const int k = k0 + j;
            if (k < DC + 8) {
                const int ds = d0 - 4 + k;
                if (ds >= 0 && ds < DIM) {     // block-uniform branch
                    const int sb = ds * PLANE;
                    // products into LDS
                    {
                        float a = 0.f, b = 0.f;
                        if (v0) { a = I[sb + off0]; b = J[sb + off0]; }
                        const int o = r0 * PSTR + c0;
                        prod[0][o] = a; prod[1][o] = b;
                        prod[2][o] = a * a; prod[3][o] = b * b; prod[4][o] = a * b;
                        if (p1 < HH * HW) {
                            float a1 = 0.f, b1 = 0.f;
                            if (v1) { a1 = I[sb + off1]; b1 = J[sb + off1]; }
                            const int o1 = r1 * PSTR + c1;
                            prod[0][o1] = a1; prod[1][o1] = b1;
                            prod[2][o1] = a1 * a1; prod[3][o1] = b1 * b1; prod[4][o1] = a1 * b1;
                        }
                    }
                    __syncthreads();
                    // sliding 9-tap W-sum: 8 outputs per task
                    if (tid < 480) {
                        float c[16];
                        #pragma unroll
                        for (int q = 0; q < 16; ++q) c[q] = prod[tf][tr * PSTR + tseg + q];
                        float s = c[0] + c[1] + c[2] + c[3] + c[4] + c[5] + c[6] + c[7] + c[8];
                        wsum[tf][tr * WSTR + tseg] = s;
                        #pragma unroll
                        for (int q = 1; q < 8; ++q) {
                            s += c[q + 8] - c[q - 1];
                            wsum[tf][tr * WSTR + tseg + q] = s;
                        }
                    }
                    __syncthreads();
                    // 9-tap H-sum -> ring + running sums
                    #pragma unroll
                    for (int f = 0; f < 5; ++f) {
                        float P = 0.f;
                        #pragma unroll
                        for (int q = 0; q < 9; ++q) P += wsum[f][(hi + q) * WSTR + wi];
                        R[f] += P - S[f][j];
                        S[f][j] = P;
                    }
                } else {
                    // zero-padded slice
                    #pragma unroll
                    for (int f = 0; f < 5; ++f) { R[f] -= S[f][j]; S[f][j] = 0.f; }
                }
                if (k >= 8) {
                    float cross = R[4] - R[0] * R[1] * INV_WS;
                    float Iv    = R[2] - R[0] * R[0] * INV_WS;
                    float Jv    = R[3] - R[1] * R[1] * INV_WS;
                    local += cross * cross / (Iv * Jv + 1e-5f);
                }
            }
        }
    }

    for (int off = 32; off; off >>= 1) local += __shfl_down(local, off);
    if ((tid & 63) == 0) {
        int wave = ((blockIdx.z * gridDim.y + blockIdx.y) * gridDim.x + blockIdx.x) * 8
                 + (tid >> 6);
        part[wave] = (double)local;
    }
}

// ---------------------------------------------------------------------------
// Gradient loss: float4 over W; forward diffs along D/H/W; per-wave partials.
// ---------------------------------------------------------------------------
__global__ void grad_kernel(const float* __restrict__ s, double* __restrict__ part) {
    const int Q = NVOX / 4;                       // float4s per channel
    const float4* s4 = (const float4*)s;
    float local = 0.f;
    for (int q = blockIdx.x * 256 + threadIdx.x; q < Q; q += gridDim.x * 256) {
        int w4   = q % (DIM / 4);
        int rest = q / (DIM / 4);
        int h = rest % DIM;
        int d = rest / DIM;
        #pragma unroll
        for (int c = 0; c < 3; ++c) {
            const int qi = c * Q + q;
            float4 v = s4[qi];
            float t;
            t = v.y - v.x; local += t * t;
            t = v.z - v.y; local += t * t;
            t = v.w - v.z; local += t * t;
            if (w4 < DIM / 4 - 1) {
                float nx = s[c * NVOX + q * 4 + 4];
                t = nx - v.w; local += t * t;
            }
            if (h < DIM - 1) {
                float4 vh = s4[qi + DIM / 4];
                t = vh.x - v.x; local += t * t;
                t = vh.y - v.y; local += t * t;
                t = vh.z - v.z; local += t * t;
                t = vh.w - v.w; local += t * t;
            }
            if (d < DIM - 1) {
                float4 vd = s4[qi + PLANE / 4];
                t = vd.x - v.x; local += t * t;
                t = vd.y - v.y; local += t * t;
                t = vd.z - v.z; local += t * t;
                t = vd.w - v.w; local += t * t;
            }
        }
    }
    for (int off = 32; off; off >>= 1) local += __shfl_down(local, off);
    if ((threadIdx.x & 63) == 0) {
        int wave = blockIdx.x * 4 + (threadIdx.x >> 6);
        part[NCC_WAVES + wave] = (double)local;
    }
}

// ---------------------------------------------------------------------------
// Final combine: sum partials; loss = 10*ncc + 15*grad.
// ---------------------------------------------------------------------------
__global__ void final_kernel(const double* __restrict__ part, float* __restrict__ out) {
    __shared__ double s_n[4], s_g[4];
    double n = 0.0, g = 0.0;
    for (int i = threadIdx.x; i < NCC_WAVES; i += 256) n += part[i];
    for (int i = threadIdx.x; i < GRAD_WAVES; i += 256) g += part[NCC_WAVES + i];
    for (int off = 32; off; off >>= 1) {
        n += __shfl_down(n, off);
        g += __shfl_down(g, off);
    }
    if ((threadIdx.x & 63) == 0) {
        s_n[threadIdx.x >> 6] = n;
        s_g[threadIdx.x >> 6] = g;
    }
    __syncthreads();
    if (threadIdx.x == 0) {
        double ncc_sum  = s_n[0] + s_n[1] + s_n[2] + s_n[3];
        double grad_sum = s_g[0] + s_g[1] + s_g[2] + s_g[3];
        double ncc  = -(ncc_sum / 4096000.0);
        double grad = grad_sum / 36633600.0;   // sum / (3*159*160*160) / 3
        double loss = 10.0 * ncc + 15.0 * grad;
        out[0] = (float)loss;
        out[1] = (float)ncc;
        out[2] = (float)grad;
    }
}

extern "C" void kernel_launch(void* const* d_in, const int* in_sizes, int n_in,
                              void* d_out, int out_size, void* d_ws, size_t ws_size,
                              hipStream_t stream) {
    const float* y    = (const float*)d_in[0];
    const float* tgt  = (const float*)d_in[1];
    // d_in[2] = src, unused by the reference
    const float* flow = (const float*)d_in[3];
    float* out = (float*)d_out;
    double* part = (double*)d_ws;   // all partial slots are written every call

    dim3 g1(DIM / TW, DIM / TH, DIM / DC);   // (5, 10, 10)
    ncc_fused_kernel<<<g1, 512, 0, stream>>>(tgt, y, part);
    grad_kernel<<<1024, 256, 0, stream>>>(flow, part);
    final_kernel<<<1, 256, 0, stream>>>(part, out);
}